// Round 2
// baseline (268.114 us; speedup 1.0000x reference)
//
#include <hip/hip_runtime.h>
#include <cstdint>
#include <cmath>

#define V_SIZE 50257
#define T_SIZE 2048
#define B_SIZE 512
#define NTHR 1024
#define NWAVE (NTHR / 64)
#define CAND_MAX 1024
#define SPEC_THRESH 10.0f
#define SPEC_MIN 80
#define KOFF 32.0f

extern "C" __global__ __launch_bounds__(NTHR, 8)
void decode_kernel(const float* __restrict__ logits,
                   const int*   __restrict__ prev,
                   const float* __restrict__ rand_u,
                   const float* __restrict__ tempp,
                   const float* __restrict__ toppp,
                   const float* __restrict__ repp,
                   float* __restrict__ out)
{
    const int row  = blockIdx.x;
    const int tid  = threadIdx.x;
    const int lane = tid & 63;
    const int wid  = tid >> 6;                  // 16 waves of 64

    __shared__ unsigned int bitmap[(V_SIZE + 31) / 32];   // 1571 words
    __shared__ float cval[CAND_MAX];
    __shared__ int   cidx[CAND_MAX];
    __shared__ float rbuf[CAND_MAX];
    __shared__ float redf[NWAVE];
    __shared__ int   redi[NWAVE];
    __shared__ float sM, sZ, sS;
    __shared__ int   sCnt, sSend;

    const float rp   = repp[0];
    const float topp = toppp[0];
    const float temp = fmaxf(tempp[0], 1e-5f);

    const size_t rowoff = (size_t)row * V_SIZE;
    const float* lrow = logits + rowoff;
    const float* urow = rand_u + rowoff;
    float*       orow = out + B_SIZE + rowoff;  // probs after 512 idx floats

    // ---- init LDS ----
    for (int i = tid; i < (V_SIZE + 31) / 32; i += NTHR) bitmap[i] = 0u;
    if (tid == 0) sCnt = 0;
    __syncthreads();

    // ---- membership bitmap of previous tokens ----
    const int4* prow4 = (const int4*)(prev + (size_t)row * T_SIZE);
    for (int i = tid; i < T_SIZE / 4; i += NTHR) {
        int4 t = prow4[i];
        atomicOr(&bitmap[((unsigned)t.x) >> 5], 1u << (t.x & 31));
        atomicOr(&bitmap[((unsigned)t.y) >> 5], 1u << (t.y & 31));
        atomicOr(&bitmap[((unsigned)t.z) >> 5], 1u << (t.z & 31));
        atomicOr(&bitmap[((unsigned)t.w) >> 5], 1u << (t.w & 31));
    }
    __syncthreads();

    // rows are not 16B aligned (V odd) -> per-row head/tail scalars
    const int head  = (4 - (row & 3)) & 3;
    const int nvec  = (V_SIZE - head) >> 2;
    const int tails = head + nvec * 4;          // start of tail scalars
    const float4* lrow4 = (const float4*)(lrow + head);
    float4*       orow4 = (float4*)(orow + head);

    // ---- pass 1: penalty + max + fixed-offset expsum + speculative collect,
    //      fused with zero-fill of the probs row (stores fly with the loads) ----
    float lm = -INFINITY, lz = 0.0f;
    auto process1 = [&](float x, int v) {
        unsigned w = bitmap[v >> 5];
        if ((w >> (v & 31)) & 1u) x = (x < 0.0f) ? x * rp : x / rp;
        if (x > SPEC_THRESH) {
            int p = atomicAdd(&sCnt, 1);
            if (p < CAND_MAX) { cval[p] = x; cidx[p] = v; }
        }
        lm = fmaxf(lm, x);
        lz += __expf(x - KOFF);                 // exact rescale later; x<=~20 so no overflow
    };
    if (tid < head)           { orow[tid] = 0.0f;          process1(lrow[tid], tid); }
    if (tid < V_SIZE - tails) { orow[tails + tid] = 0.0f;  process1(lrow[tails + tid], tails + tid); }
    {
        float4 z4 = make_float4(0.f, 0.f, 0.f, 0.f);
        for (int i = tid; i < nvec; i += NTHR) {
            orow4[i] = z4;                      // fire-and-forget store
            float4 x4 = lrow4[i];
            int v = head + i * 4;
            process1(x4.x, v); process1(x4.y, v + 1);
            process1(x4.z, v + 2); process1(x4.w, v + 3);
        }
    }

    // ---- block reduce M ----
    {
        float wm = lm;
        for (int off = 32; off; off >>= 1) wm = fmaxf(wm, __shfl_down(wm, off));
        if (lane == 0) redf[wid] = wm;
    }
    __syncthreads();
    if (tid == 0) {
        float m = redf[0];
        for (int i = 1; i < NWAVE; ++i) m = fmaxf(m, redf[i]);
        sM = m;
    }
    __syncthreads();
    const float M = sM;

    // ---- block reduce S = sum exp(x - KOFF); Z = S * e^(KOFF - M) ----
    {
        float wz = lz;
        for (int off = 32; off; off >>= 1) wz += __shfl_down(wz, off);
        if (lane == 0) redf[wid] = wz;
    }
    __syncthreads();
    if (tid == 0) {
        float s = 0.0f;
        for (int i = 0; i < NWAVE; ++i) s += redf[i];
        sZ = s * expf(KOFF - M);
    }
    __syncthreads();
    const float Z = sZ;

    // ---- candidate set: speculative {x > 10}; bisection fallback (≈never) ----
    int cnt = sCnt;                              // ordered by the barriers above
    int C;
    if (cnt >= SPEC_MIN && cnt <= CAND_MAX) {
        C = cnt;                                 // exact value-prefix of the row
    } else {
        auto count_pass = [&](float thr) -> int {
            __syncthreads();
            if (tid == 0) sCnt = 0;
            __syncthreads();
            int local = 0;
            for (int v = tid; v < V_SIZE; v += NTHR) {
                float x = lrow[v];
                unsigned w = bitmap[v >> 5];
                if ((w >> (v & 31)) & 1u) x = (x < 0.0f) ? x * rp : x / rp;
                if (x > thr) local++;
            }
            if (local) atomicAdd(&sCnt, local);
            __syncthreads();
            return sCnt;
        };
        float a = -200.0f, b = 200.0f, thr = 0.0f;
        int c = 0;
        for (int it = 0; it < 40; ++it) {
            thr = 0.5f * (a + b);
            c = count_pass(thr);
            if (c < SPEC_MIN)       b = thr;
            else if (c > CAND_MAX)  a = thr;
            else break;
        }
        if (c < SPEC_MIN) thr = a;               // last side with enough mass
        __syncthreads();
        if (tid == 0) sCnt = 0;
        __syncthreads();
        for (int v = tid; v < V_SIZE; v += NTHR) {
            float x = lrow[v];
            unsigned w = bitmap[v >> 5];
            if ((w >> (v & 31)) & 1u) x = (x < 0.0f) ? x * rp : x / rp;
            if (x > thr) {
                int p = atomicAdd(&sCnt, 1);
                if (p < CAND_MAX) { cval[p] = x; cidx[p] = v; }
            }
        }
        __syncthreads();
        C = min(sCnt, CAND_MAX);
    }

    // ---- bitonic sort candidates: descending value, tie -> ascending index ----
    int n = 1; while (n < C) n <<= 1;            // n in [128,1024]
    for (int i = C + tid; i < n; i += NTHR) { cval[i] = -INFINITY; cidx[i] = 0x7FFFFFFF; }
    __syncthreads();
    for (int k = 2; k <= n; k <<= 1) {
        for (int j = k >> 1; j > 0; j >>= 1) {
            for (int i = tid; i < n; i += NTHR) {
                int l = i ^ j;
                if (l > i) {
                    float vi = cval[i], vl = cval[l];
                    int   ii = cidx[i], il = cidx[l];
                    bool lFirst = (vl > vi) || (vl == vi && il < ii);
                    bool asc = ((i & k) == 0);
                    if (lFirst == asc) {
                        cval[i] = vl; cval[l] = vi;
                        cidx[i] = il; cidx[l] = ii;
                    }
                }
            }
            __syncthreads();
        }
    }

    // ---- serial decision: top-p prefix m, top-50 pivot tie-run e ----
    if (tid == 0) {
        float cum = 0.0f;
        int m = 0;
        float vp = cval[min(49, C - 1)];
        for (int i = 0; i < C; ++i) {
            cum += expf(cval[i] - M) / Z;
            if (i > 0 && cum > topp) break;      // suffix removed; m final
            m = i;
            if (m >= 49 && cval[i] < vp) break;  // past pivot tie-run; support=e
        }
        int send;
        if (m >= 49) {
            int e = 49;
            while (e + 1 < C && cval[e + 1] == vp) ++e;
            send = (m < e) ? m : e;
        } else {
            send = m;
        }
        sSend = send;
    }
    __syncthreads();

    // ---- final softmax over support (temperature applied), scatter, sample ----
    const int send = sSend;
    const float v0 = cval[0];                    // row max (position 0)
    for (int i = tid; i <= send; i += NTHR)
        rbuf[i] = expf(cval[i] / temp - v0 / temp);
    __syncthreads();
    if (tid == 0) {
        float S = 0.0f;
        for (int i = 0; i <= send; ++i) S += rbuf[i];
        sS = S;
    }
    __syncthreads();
    const float S = sS;

    float bestr = -1.0f;
    int   besti = 0x7FFFFFFF;
    for (int i = tid; i <= send; i += NTHR) {
        float p = rbuf[i] / S;
        int v = cidx[i];
        orow[v] = p;                             // overwrite zero (ordered by barriers)
        float q = -logf(urow[v]);
        float r = p / q;
        if (r > bestr || (r == bestr && v < besti)) { bestr = r; besti = v; }
    }
    for (int off = 32; off; off >>= 1) {
        float r2 = __shfl_down(bestr, off);
        int   i2 = __shfl_down(besti, off);
        if (r2 > bestr || (r2 == bestr && i2 < besti)) { bestr = r2; besti = i2; }
    }
    if (lane == 0) { redf[wid] = bestr; redi[wid] = besti; }
    __syncthreads();
    if (tid == 0) {
        float br = redf[0]; int bi = redi[0];
        for (int i = 1; i < NWAVE; ++i) {
            if (redf[i] > br || (redf[i] == br && redi[i] < bi)) { br = redf[i]; bi = redi[i]; }
        }
        out[row] = (float)bi;                    // idx as f32 (exact for < 2^24)
    }
}

extern "C" void kernel_launch(void* const* d_in, const int* in_sizes, int n_in,
                              void* d_out, int out_size, void* d_ws, size_t ws_size,
                              hipStream_t stream) {
    const float* logits = (const float*)d_in[0];
    const int*   prev   = (const int*)d_in[1];
    const float* rand_u = (const float*)d_in[2];
    const float* tempp  = (const float*)d_in[3];
    const float* toppp  = (const float*)d_in[4];
    const float* repp   = (const float*)d_in[5];
    float* out = (float*)d_out;
    hipLaunchKernelGGL(decode_kernel, dim3(B_SIZE), dim3(NTHR), 0, stream,
                       logits, prev, rand_u, tempp, toppp, repp, out);
}

// Round 3
// 261.482 us; speedup vs baseline: 1.0254x; 1.0254x over previous
//
#include <hip/hip_runtime.h>
#include <cstdint>
#include <cmath>

#define V_SIZE 50257
#define T_SIZE 2048
#define B_SIZE 512
#define NTHR 1024
#define NWAVE (NTHR / 64)
#define CAND_MAX 1024
#define SPEC_THRESH 10.0f
#define SPEC_MIN 80
#define KOFF 32.0f

extern "C" __global__ __launch_bounds__(NTHR, 8)
void decode_kernel(const float* __restrict__ logits,
                   const int*   __restrict__ prev,
                   const float* __restrict__ rand_u,
                   const float* __restrict__ tempp,
                   const float* __restrict__ toppp,
                   const float* __restrict__ repp,
                   float* __restrict__ out)
{
    const int row  = blockIdx.x;
    const int tid  = threadIdx.x;
    const int lane = tid & 63;
    const int wid  = tid >> 6;                  // 16 waves of 64

    __shared__ unsigned int bitmap[(V_SIZE + 31) / 32];   // 1571 words
    __shared__ float cval[CAND_MAX];
    __shared__ int   cidx[CAND_MAX];
    __shared__ float rbuf[CAND_MAX];
    __shared__ float redf[NWAVE];
    __shared__ int   redi[NWAVE];
    __shared__ float sM, sZ, sS;
    __shared__ int   sCnt, sSend;

    const float rp   = repp[0];
    const float topp = toppp[0];
    const float temp = fmaxf(tempp[0], 1e-5f);

    const size_t rowoff = (size_t)row * V_SIZE;
    const float* lrow = logits + rowoff;
    const float* urow = rand_u + rowoff;
    float*       orow = out + B_SIZE + rowoff;  // probs after 512 idx floats

    // ---- init LDS ----
    for (int i = tid; i < (V_SIZE + 31) / 32; i += NTHR) bitmap[i] = 0u;
    if (tid == 0) sCnt = 0;
    __syncthreads();

    // ---- membership bitmap of previous tokens ----
    const int4* prow4 = (const int4*)(prev + (size_t)row * T_SIZE);
    for (int i = tid; i < T_SIZE / 4; i += NTHR) {
        int4 t = prow4[i];
        atomicOr(&bitmap[((unsigned)t.x) >> 5], 1u << (t.x & 31));
        atomicOr(&bitmap[((unsigned)t.y) >> 5], 1u << (t.y & 31));
        atomicOr(&bitmap[((unsigned)t.z) >> 5], 1u << (t.z & 31));
        atomicOr(&bitmap[((unsigned)t.w) >> 5], 1u << (t.w & 31));
    }
    __syncthreads();

    // rows are not 16B aligned (V odd) -> per-row head/tail scalars
    const int head  = (4 - (row & 3)) & 3;
    const int nvec  = (V_SIZE - head) >> 2;
    const int tails = head + nvec * 4;          // start of tail scalars
    const float4* lrow4 = (const float4*)(lrow + head);

    // ---- pass 1 (READ-ONLY stream): penalty + max + fixed-offset expsum +
    //      speculative candidate collect. No stores in the hot loop: the
    //      float4 loads can software-pipeline freely. ----
    float lm = -INFINITY, lz = 0.0f;
    auto process1 = [&](float x, int v) {
        unsigned w = bitmap[v >> 5];
        if ((w >> (v & 31)) & 1u) x = (x < 0.0f) ? x * rp : x / rp;
        if (x > SPEC_THRESH) {
            int p = atomicAdd(&sCnt, 1);
            if (p < CAND_MAX) { cval[p] = x; cidx[p] = v; }
        }
        lm = fmaxf(lm, x);
        lz += __expf(x - KOFF);                 // exact rescale later; x<=~20 so no overflow
    };
    if (tid < head)           process1(lrow[tid], tid);
    if (tid < V_SIZE - tails) process1(lrow[tails + tid], tails + tid);
    for (int i = tid; i < nvec; i += NTHR) {
        float4 x4 = lrow4[i];
        int v = head + i * 4;
        process1(x4.x, v); process1(x4.y, v + 1);
        process1(x4.z, v + 2); process1(x4.w, v + 3);
    }

    // ---- block reduce M ----
    {
        float wm = lm;
        for (int off = 32; off; off >>= 1) wm = fmaxf(wm, __shfl_down(wm, off));
        if (lane == 0) redf[wid] = wm;
    }
    __syncthreads();
    if (tid == 0) {
        float m = redf[0];
        for (int i = 1; i < NWAVE; ++i) m = fmaxf(m, redf[i]);
        sM = m;
    }
    __syncthreads();
    const float M = sM;

    // ---- block reduce S = sum exp(x - KOFF); Z = S * e^(KOFF - M) ----
    {
        float wz = lz;
        for (int off = 32; off; off >>= 1) wz += __shfl_down(wz, off);
        if (lane == 0) redf[wid] = wz;
    }
    __syncthreads();
    if (tid == 0) {
        float s = 0.0f;
        for (int i = 0; i < NWAVE; ++i) s += redf[i];
        sZ = s * expf(KOFF - M);
    }
    __syncthreads();
    const float Z = sZ;

    // ---- candidate set: speculative {x > 10}; bisection fallback (≈never) ----
    int cnt = sCnt;                              // ordered by the barriers above
    int C;
    if (cnt >= SPEC_MIN && cnt <= CAND_MAX) {
        C = cnt;                                 // exact value-prefix of the row
    } else {
        auto count_pass = [&](float thr) -> int {
            __syncthreads();
            if (tid == 0) sCnt = 0;
            __syncthreads();
            int local = 0;
            for (int v = tid; v < V_SIZE; v += NTHR) {
                float x = lrow[v];
                unsigned w = bitmap[v >> 5];
                if ((w >> (v & 31)) & 1u) x = (x < 0.0f) ? x * rp : x / rp;
                if (x > thr) local++;
            }
            if (local) atomicAdd(&sCnt, local);
            __syncthreads();
            return sCnt;
        };
        float a = -200.0f, b = 200.0f, thr = 0.0f;
        int c = 0;
        for (int it = 0; it < 40; ++it) {
            thr = 0.5f * (a + b);
            c = count_pass(thr);
            if (c < SPEC_MIN)       b = thr;
            else if (c > CAND_MAX)  a = thr;
            else break;
        }
        if (c < SPEC_MIN) thr = a;               // last side with enough mass
        __syncthreads();
        if (tid == 0) sCnt = 0;
        __syncthreads();
        for (int v = tid; v < V_SIZE; v += NTHR) {
            float x = lrow[v];
            unsigned w = bitmap[v >> 5];
            if ((w >> (v & 31)) & 1u) x = (x < 0.0f) ? x * rp : x / rp;
            if (x > thr) {
                int p = atomicAdd(&sCnt, 1);
                if (p < CAND_MAX) { cval[p] = x; cidx[p] = v; }
            }
        }
        __syncthreads();
        C = min(sCnt, CAND_MAX);
    }

    // ---- bitonic sort candidates: descending value, tie -> ascending index ----
    int n = 1; while (n < C) n <<= 1;            // n in [128,1024]
    for (int i = C + tid; i < n; i += NTHR) { cval[i] = -INFINITY; cidx[i] = 0x7FFFFFFF; }
    __syncthreads();
    for (int k = 2; k <= n; k <<= 1) {
        for (int j = k >> 1; j > 0; j >>= 1) {
            for (int i = tid; i < n; i += NTHR) {
                int l = i ^ j;
                if (l > i) {
                    float vi = cval[i], vl = cval[l];
                    int   ii = cidx[i], il = cidx[l];
                    bool lFirst = (vl > vi) || (vl == vi && il < ii);
                    bool asc = ((i & k) == 0);
                    if (lFirst == asc) {
                        cval[i] = vl; cval[l] = vi;
                        cidx[i] = il; cidx[l] = ii;
                    }
                }
            }
            __syncthreads();
        }
    }

    // ---- serial decision: top-p prefix m, top-50 pivot tie-run e ----
    if (tid == 0) {
        float cum = 0.0f;
        int m = 0;
        float vp = cval[min(49, C - 1)];
        for (int i = 0; i < C; ++i) {
            cum += expf(cval[i] - M) / Z;
            if (i > 0 && cum > topp) break;      // suffix removed; m final
            m = i;
            if (m >= 49 && cval[i] < vp) break;  // past pivot tie-run; support=e
        }
        int send;
        if (m >= 49) {
            int e = 49;
            while (e + 1 < C && cval[e + 1] == vp) ++e;
            send = (m < e) ? m : e;
        } else {
            send = m;
        }
        sSend = send;
    }
    __syncthreads();

    // ---- final softmax over support (temperature applied), scatter, sample ----
    const int send = sSend;
    const float v0 = cval[0];                    // row max (position 0)
    for (int i = tid; i <= send; i += NTHR)
        rbuf[i] = expf(cval[i] / temp - v0 / temp);
    __syncthreads();
    if (tid == 0) {
        float S = 0.0f;
        for (int i = 0; i <= send; ++i) S += rbuf[i];
        sS = S;
    }
    __syncthreads();
    const float S = sS;

    float bestr = -1.0f;
    int   besti = 0x7FFFFFFF;
    for (int i = tid; i <= send; i += NTHR) {
        float p = rbuf[i] / S;
        int v = cidx[i];
        orow[v] = p;                             // only nonzero probs; memset did the rest
        float q = -logf(urow[v]);
        float r = p / q;
        if (r > bestr || (r == bestr && v < besti)) { bestr = r; besti = v; }
    }
    for (int off = 32; off; off >>= 1) {
        float r2 = __shfl_down(bestr, off);
        int   i2 = __shfl_down(besti, off);
        if (r2 > bestr || (r2 == bestr && i2 < besti)) { bestr = r2; besti = i2; }
    }
    if (lane == 0) { redf[wid] = bestr; redi[wid] = besti; }
    __syncthreads();
    if (tid == 0) {
        float br = redf[0]; int bi = redi[0];
        for (int i = 1; i < NWAVE; ++i) {
            if (redf[i] > br || (redf[i] == br && redi[i] < bi)) { br = redf[i]; bi = redi[i]; }
        }
        out[row] = (float)bi;                    // idx as f32 (exact for < 2^24)
    }
}

extern "C" void kernel_launch(void* const* d_in, const int* in_sizes, int n_in,
                              void* d_out, int out_size, void* d_ws, size_t ws_size,
                              hipStream_t stream) {
    const float* logits = (const float*)d_in[0];
    const int*   prev   = (const int*)d_in[1];
    const float* rand_u = (const float*)d_in[2];
    const float* tempp  = (const float*)d_in[3];
    const float* toppp  = (const float*)d_in[4];
    const float* repp   = (const float*)d_in[5];
    float* out = (float*)d_out;

    // Zero the entire output (idx area + probs) with a driver-optimized
    // pure-write memset node; the kernel then scatters only the <=51
    // nonzero probs per row and the sampled index.
    hipMemsetAsync(d_out, 0, (size_t)out_size * sizeof(float), stream);

    hipLaunchKernelGGL(decode_kernel, dim3(B_SIZE), dim3(NTHR), 0, stream,
                       logits, prev, rand_u, tempp, toppp, repp, out);
}